// Round 11
// baseline (864.250 us; speedup 1.0000x reference)
//
#include <hip/hip_runtime.h>
#include <hip/hip_bf16.h>
#include <stdint.h>

typedef __bf16 bf16;
typedef __bf16 bf16x8 __attribute__((ext_vector_type(8)));
typedef float f32x4 __attribute__((ext_vector_type(4)));
typedef unsigned short u16t;
typedef unsigned int u32t;

#define MFMA16(a, b, c) __builtin_amdgcn_mfma_f32_16x16x32_bf16((a), (b), (c), 0, 0, 0)

typedef const void __attribute__((address_space(1))) cg_void;
typedef void __attribute__((address_space(3))) lds_void;
#define GLL16(g, l) __builtin_amdgcn_global_load_lds((cg_void*)(g), (lds_void*)(l), 16, 0, 0)
#define VWAIT(n) asm volatile("s_waitcnt vmcnt(" #n ")" ::: "memory")

// ---------------- ws layout (bytes) ----------------
#define OFF_FLAG   0
#define OFF_BQKV   256
#define OFF_BPROJ  6400
#define OFF_WQKVT  8448
#define OFF_WPROJT 1581312
#define OFF_QKV    2105600      // attn-out (134 MB; qkv never materialized)
#define OFF_XB     404758784    // xb (bf16 x, 134 MB)

// head-triple permutation: reordered-W^T row n <- original qkv col src(n)
// h = n/96, r = n%96, part = r/32 (0=Q,1=K,2=V), d = r%32; src = part*512 + h*32 + d

// Paired-row LDS layout (R3-proven 0-conflict geometry, applied to BK=32):
// LDS-row R (128 B = 8 chunks of 16 B) holds tokens 2R,2R+1 of the tile.
// logical chunk c: token-part = c>>2, k-octet = c&3. phys chunk = c ^ (R&7).
// Staged via GLL16 linear dest + inverse-swizzled per-lane source (rule 21):
// lane l of an inst with base LDS-row Rs (Rs%8==0): R = Rs+(l>>3),
// c = (l&7)^(l>>3), token = 2R+(c>>2), k-off (c&3)*8.
// Frag read: token r, k-octet qd -> R = r>>1, c = (r&1)*4+qd,
// phys = c ^ ((r>>1)&7); per 128-B row the 8 sharing lanes cover all 8 slots.

// ---------------- dtype detector ----------------
__global__ __launch_bounds__(256) void k_detect(const u16t* x, u32t* flag) {
    __shared__ int cnt;
    if (threadIdx.x == 0) cnt = 0;
    __syncthreads();
    u16t h = x[threadIdx.x * 2];
    int e = (h >> 7) & 0xFF;
    int ok = (h == 0) || (e >= 100 && e <= 134);
    atomicAdd(&cnt, ok);
    __syncthreads();
    if (threadIdx.x == 0) flag[0] = (cnt >= 200) ? 1u : 0u;
}

// ---------------- x f32 -> bf16 pre-pass (skipped when input already bf16) ----
__global__ __launch_bounds__(256) void k_cvt(const float* x, bf16* xb, const u32t* flagp) {
    if (flagp[0]) return;
    const size_t TOT = (size_t)131072 * 512;
    size_t i = (size_t)(blockIdx.x * 256 + threadIdx.x) * 8;
    const size_t stride = (size_t)gridDim.x * 256 * 8;
    for (; i < TOT; i += stride) {
        float4 v0 = *(const float4*)(x + i);
        float4 v1 = *(const float4*)(x + i + 4);
        bf16x8 h;
        h[0] = (bf16)v0.x; h[1] = (bf16)v0.y; h[2] = (bf16)v0.z; h[3] = (bf16)v0.w;
        h[4] = (bf16)v1.x; h[5] = (bf16)v1.y; h[6] = (bf16)v1.z; h[7] = (bf16)v1.w;
        *(bf16x8*)(xb + i) = h;
    }
}

// ---------------- weight transpose: W[512][N] -> Wt[N][512] bf16 ----------------
template <int N, bool PERM>
__global__ __launch_bounds__(256) void k_trans(const void* W, bf16* Wt, const u32t* flagp) {
    __shared__ float T[64][65];
    const int isbf = (int)flagp[0];
    const int n0 = blockIdx.x * 64, k0 = blockIdx.y * 64;
    const int t = threadIdx.x;
    const int lc = t & 63, lr = t >> 6;
#pragma unroll
    for (int rr = 0; rr < 16; ++rr) {
        int row = rr * 4 + lr;
        int col = n0 + lc;
        int srcc = col;
        if (PERM) {
            int h = col / 96, r = col % 96;
            srcc = (r >> 5) * 512 + h * 32 + (r & 31);
        }
        size_t g = (size_t)(k0 + row) * N + srcc;
        float v = isbf ? (float)((const bf16*)W)[g] : ((const float*)W)[g];
        T[row][lc] = v;
    }
    __syncthreads();
#pragma unroll
    for (int rr = 0; rr < 16; ++rr) {
        int row = rr * 4 + lr;
        Wt[(size_t)(n0 + row) * 512 + k0 + lc] = (bf16)T[lc][row];
    }
}

// ---------------- bias prep -> f32 (bq permuted to head-triple order) ----------
__global__ __launch_bounds__(256) void k_bias(const void* b_qkv, const void* b_proj,
                                              const u32t* flagp, char* ws) {
    float* bq = (float*)(ws + OFF_BQKV);
    float* bp = (float*)(ws + OFF_BPROJ);
    const int isbf = (int)flagp[0];
    int gid = blockIdx.x * 256 + threadIdx.x;
    if (gid < 1536) {
        int h = gid / 96, r = gid % 96;
        int src = (r >> 5) * 512 + h * 32 + (r & 31);
        bq[gid] = isbf ? (float)((const bf16*)b_qkv)[src] : ((const float*)b_qkv)[src];
    } else if (gid < 2048) {
        int o = gid - 1536;
        bp[o] = isbf ? (float)((const bf16*)b_proj)[o] : ((const float*)b_proj)[o];
    }
}

// ---------------- proj GEMM: 256^2 tile, BK=32 paired-row, 64 KB -> 2 blk/CU --
// 512 thr = 8 waves (wm = w>>2, wn = w&3). K=512 -> 16 tiles, 4 phases
// (QM,QN quadrants), 8 MFMA each. Stage units = 1 GLL16/wave (BK=32 halves
// the tile: 64 LDS-rows per unit = 8 waves x 8 rows). Coverage (verified
// bijective, all bases ==0 mod 8):
//   A-s: RsA = s*32+(w>>2)*64+(w&3)*8 -> rows [s*32,+32) u [64+s*32,+32)
//        = tokens of quadrant QM=s.
//   B-s: RsB = s*16+(w>>1)*32+(w&1)*8 -> rows {32c+s*16+[0,16)} = cols of QN=s.
// Ledger (4 loads/wave/tile, issue order A0@P00,B0@P01,B1@P10,A1@P11;
// one-phase lookahead -- wait in phase p covers phase p+1's ds_reads):
//   P00: VWAIT(2) -> B1(t); P01: VWAIT(2) -> A1(t); P10: none;
//   P11: VWAIT(2) -> A0,B0(t+1). Tail t=15: (1),(0),-,-. Prologue VWAIT(2).
// Never drains mid-loop. Stage targets buffer last read >=2 barriers earlier.
// Per-acc K-order: 16 ascending 32-steps == old 8x{kk0,kk1} -> absmax identical.
template <int NTOT>
__global__ __launch_bounds__(512, 2) void k_gemm(const void* Ax, const bf16* Axb, const bf16* Bt,
                                                 const float* bias, void* Cp,
                                                 const u32t* flagp, int omode) {
    __shared__ __align__(16) u16t As[2 * 8192];
    __shared__ __align__(16) u16t Bs[2 * 8192];
    constexpr int NBN = NTOT / 256;
    const int isbf = (int)flagp[0];
    const int out_bf16 = (omode == 1) || isbf;
    const bf16* Ab = isbf ? (const bf16*)Ax : Axb;

    const int t = threadIdx.x;
    const int w = t >> 6, lane = t & 63;
    const int ln = lane & 15, qd = lane >> 4;
    const int wm = w >> 2, wn = w & 3;

    const int flat = blockIdx.x;
    const int xcd = flat & 7, slot = flat >> 3;
    const int n_idx = slot % NBN, grp = slot / NBN;
    const int m0 = (grp * 8 + xcd) * 256;
    const int n0 = n_idx * 256;

    // staging source (inverse swizzle, paired-row)
    const int l8 = lane >> 3, p8 = lane & 7;
    const int cl = p8 ^ l8;
    const int tok_l = 2 * l8 + (cl >> 2);
    const int koff = (cl & 3) * 8;

    u32t asrc[2], bsrc[2];
    int adst[2], bdst[2];
#pragma unroll
    for (int s = 0; s < 2; ++s) {
        int RsA = s * 32 + (w >> 2) * 64 + (w & 3) * 8;
        asrc[s] = (u32t)(m0 + 2 * RsA + tok_l) * 512 + koff;
        adst[s] = RsA * 64;
        int RsB = s * 16 + (w >> 1) * 32 + (w & 1) * 8;
        bsrc[s] = (u32t)(n0 + 2 * RsB + tok_l) * 512 + koff;
        bdst[s] = RsB * 64;
    }

    // fragment bases: A token = QM*64+wm*128+i*16+ln; B col = QN*32+wn*64+j*16+ln
    const int fph = (((ln & 1) * 4 + qd) ^ ((ln >> 1) & 7)) * 8;
    int abase[4], bbase[2];
#pragma unroll
    for (int i = 0; i < 4; ++i) abase[i] = (wm * 64 + i * 8 + (ln >> 1)) * 64 + fph;
#pragma unroll
    for (int j = 0; j < 2; ++j) bbase[j] = (wn * 32 + j * 8 + (ln >> 1)) * 64 + fph;

    f32x4 acc[8][4];
    f32x4 zero = {0.f, 0.f, 0.f, 0.f};
#pragma unroll
    for (int i = 0; i < 8; ++i)
#pragma unroll
        for (int j = 0; j < 4; ++j) acc[i][j] = zero;

    auto stageA = [&](int s, int buf, int kt) {
        GLL16(Ab + asrc[s] + kt * 32, &As[buf * 8192 + adst[s]]);
    };
    auto stageB = [&](int s, int buf, int kt) {
        GLL16(Bt + bsrc[s] + kt * 32, &Bs[buf * 8192 + bdst[s]]);
    };

#define PHX(BUF, QM, QN, LOADA, STG, WAITOP)                                    \
    {                                                                           \
        if (LOADA) {                                                            \
            _Pragma("unroll") for (int i = 0; i < 4; ++i)                       \
                af[i] = *(const bf16x8*)(const void*)                           \
                    &As[(BUF) * 8192 + (QM) * 2048 + abase[i]];                 \
        }                                                                       \
        _Pragma("unroll") for (int j = 0; j < 2; ++j)                           \
            bv[j] = *(const bf16x8*)(const void*)                               \
                &Bs[(BUF) * 8192 + (QN) * 1024 + bbase[j]];                     \
        STG;                                                                    \
        WAITOP;                                                                 \
        __builtin_amdgcn_s_barrier();                                           \
        __builtin_amdgcn_s_setprio(1);                                          \
        _Pragma("unroll") for (int i = 0; i < 4; ++i)                           \
            _Pragma("unroll") for (int j = 0; j < 2; ++j)                       \
                acc[(QM) * 4 + i][(QN) * 2 + j] =                               \
                    MFMA16(af[i], bv[j], acc[(QM) * 4 + i][(QN) * 2 + j]);      \
        __builtin_amdgcn_s_setprio(0);                                          \
        __builtin_amdgcn_s_barrier();                                           \
    }

    stageA(0, 0, 0);
    stageB(0, 0, 0);
    stageB(1, 0, 0);
    stageA(1, 0, 0);
    VWAIT(2);
    __builtin_amdgcn_s_barrier();

    for (int kt = 0; kt < 16; ++kt) {
        const int buf = kt & 1, nb = buf ^ 1, k1 = kt + 1;
        bf16x8 af[4], bv[2];
        if (kt < 15) {
            PHX(buf, 0, 0, 1, stageA(0, nb, k1), VWAIT(2));
            PHX(buf, 0, 1, 0, stageB(0, nb, k1), VWAIT(2));
            PHX(buf, 1, 0, 1, stageB(1, nb, k1), (void)0);
            PHX(buf, 1, 1, 0, stageA(1, nb, k1), VWAIT(2));
        } else {
            PHX(buf, 0, 0, 1, (void)0, VWAIT(1));
            PHX(buf, 0, 1, 0, (void)0, VWAIT(0));
            PHX(buf, 1, 0, 1, (void)0, (void)0);
            PHX(buf, 1, 1, 0, (void)0, (void)0);
        }
    }
#undef PHX

    float bj[4];
#pragma unroll
    for (int j = 0; j < 4; ++j) bj[j] = bias[n0 + wn * 64 + j * 16 + ln];

    if (out_bf16) {
        bf16* C = (bf16*)Cp;
#pragma unroll
        for (int i = 0; i < 8; ++i)
#pragma unroll
            for (int j = 0; j < 4; ++j)
#pragma unroll
                for (int rr = 0; rr < 4; ++rr) {
                    size_t row = (size_t)m0 + wm * 128 + i * 16 + qd * 4 + rr;
                    int col = n0 + wn * 64 + j * 16 + ln;
                    C[row * NTOT + col] = (bf16)(acc[i][j][rr] + bj[j]);
                }
    } else {
        float* C = (float*)Cp;
#pragma unroll
        for (int i = 0; i < 8; ++i)
#pragma unroll
            for (int j = 0; j < 4; ++j)
#pragma unroll
                for (int rr = 0; rr < 4; ++rr) {
                    size_t row = (size_t)m0 + wm * 128 + i * 16 + qd * 4 + rr;
                    int col = n0 + wn * 64 + j * 16 + ln;
                    C[row * NTOT + col] = acc[i][j][rr] + bj[j];
                }
    }
}

// ---------------- FUSE5: fuse4 with paired-row 128-B-stripe LDS layout --------
// Identical structure/ledger to fuse4 (BK=32, 3 phases, waits (4,4,2)/tail
// (1,0,-), prologue VWAIT(2), 53 KB pool, 3 blocks/CU, wave-private attention).
// Only the LDS layout changes: A [64 LDS-rows][64], B [96 LDS-rows][64],
// 8-chunk XOR swizzle -> frag ds_read_b128 conflict-free (R3-proven geometry).
__global__ __launch_bounds__(256, 3) void k_fuse5(const void* Ax, const bf16* Axb,
                                                  const bf16* Bt, const float* bias,
                                                  bf16* attnout, const u32t* flagp) {
    __shared__ __align__(16) u16t pool[26624];   // A 2x4096 @0; B 2x6144 @8192
    const int isbf = (int)flagp[0];
    const bf16* Ab = isbf ? (const bf16*)Ax : Axb;

    const int t = threadIdx.x;
    const int w = t >> 6, lane = t & 63;
    const int ln = lane & 15, qd = lane >> 4, q8 = qd * 8;
    const int wm = w >> 1, wn = w & 1;

    const int flat = blockIdx.x;
    const int xcd = flat & 7, slot = flat >> 3;
    const int n_idx = slot & 7, mgrp = slot >> 3;
    const int blkm = mgrp * 8 + xcd;             // 0..1023 (bijective)
    const int m0 = blkm * 128;
    const int n0 = n_idx * 192;
    const int win = blkm * 2 + wm;
    const int g = n_idx * 2 + wn;

    // staging source (inverse swizzle, paired-row)
    const int l8 = lane >> 3, p8 = lane & 7;
    const int cl = p8 ^ l8;
    const int tok_l = 2 * l8 + (cl >> 2);
    const int koff = (cl & 3) * 8;

    // A: 2 insts/wave; inst q base LDS-row w*16+q*8 (covers rows [0,64))
    u32t asrc[2];
    int adst[2];
#pragma unroll
    for (int q = 0; q < 2; ++q) {
        int Rs = w * 16 + q * 8;
        asrc[q] = (u32t)(m0 + 2 * Rs + tok_l) * 512 + koff;
        adst[q] = Rs * 64;
    }
    // B: 1 inst/wave/region; region r covers LDS-rows [r*16,+16)u[48+r*16,+16)
    u32t bsrc[3];
    int bdst[3];
#pragma unroll
    for (int r = 0; r < 3; ++r) {
        int Rs = (w & 1) * 48 + r * 16 + (w >> 1) * 8;
        bsrc[r] = (u32t)(n0 + 2 * Rs + tok_l) * 512 + koff;
        bdst[r] = Rs * 64;
    }

    // fragment bases
    const int fph = (((ln & 1) * 4 + qd) ^ ((ln >> 1) & 7)) * 8;
    int afo[4], bfo[6];
#pragma unroll
    for (int i = 0; i < 4; ++i) afo[i] = (wm * 32 + i * 8 + (ln >> 1)) * 64 + fph;
#pragma unroll
    for (int j = 0; j < 6; ++j) bfo[j] = (wn * 48 + j * 8 + (ln >> 1)) * 64 + fph;

    f32x4 acc[4][6];
    f32x4 zero = {0.f, 0.f, 0.f, 0.f};
#pragma unroll
    for (int i = 0; i < 4; ++i)
#pragma unroll
        for (int j = 0; j < 6; ++j) acc[i][j] = zero;

    auto ST_A = [&](int buf, int kt) {
#pragma unroll
        for (int q = 0; q < 2; ++q)
            GLL16(Ab + asrc[q] + kt * 32, &pool[buf * 4096 + adst[q]]);
    };
    auto ST_R = [&](int r, int buf, int kt) {
        GLL16(Bt + bsrc[r] + kt * 32, &pool[8192 + buf * 6144 + bdst[r]]);
    };

    // prologue: tile 0 -> buf 0 (order A,A,R0,R1,R2); A+R0 needed -> VWAIT(2)
    ST_A(0, 0);
    ST_R(0, 0, 0);
    ST_R(1, 0, 0);
    ST_R(2, 0, 0);
    VWAIT(2);
    __builtin_amdgcn_s_barrier();

    for (int kt = 0; kt < 16; ++kt) {
        const int buf = kt & 1, nb = buf ^ 1;
        const u16t* Abuf = &pool[buf * 4096];
        const u16t* Bbuf = &pool[8192 + buf * 6144];
        bf16x8 af[4], bv[2];

        // ---- P0: A-frags + j{0,1} ----
#pragma unroll
        for (int i = 0; i < 4; ++i)
            af[i] = *(const bf16x8*)(const void*)&Abuf[afo[i]];
        bv[0] = *(const bf16x8*)(const void*)&Bbuf[bfo[0]];
        bv[1] = *(const bf16x8*)(const void*)&Bbuf[bfo[1]];
        if (kt < 15) { ST_A(nb, kt + 1); ST_R(0, nb, kt + 1); VWAIT(4); }
        else VWAIT(1);
        __builtin_amdgcn_s_barrier();
        __builtin_amdgcn_s_setprio(1);
#pragma unroll
        for (int i = 0; i < 4; ++i) {
            acc[i][0] = MFMA16(af[i], bv[0], acc[i][0]);
            acc[i][1] = MFMA16(af[i], bv[1], acc[i][1]);
        }
        __builtin_amdgcn_s_setprio(0);
        __builtin_amdgcn_s_barrier();

        // ---- P1: j{2,3} ----
        bv[0] = *(const bf16x8*)(const void*)&Bbuf[bfo[2]];
        bv[1] = *(const bf16x8*)(const void*)&Bbuf[bfo[3]];
        if (kt < 15) { ST_R(1, nb, kt + 1); VWAIT(4); }
        else VWAIT(0);
        __builtin_amdgcn_s_barrier();
        __builtin_amdgcn_s_setprio(1);
#pragma unroll
        for (int i = 0; i < 4; ++i) {
            acc[i][2] = MFMA16(af[i], bv[0], acc[i][2]);
            acc[i][3] = MFMA16(af[i], bv[1], acc[i][3]);
        }
        __builtin_amdgcn_s_setprio(0);
        __builtin_amdgcn_s_barrier();

        // ---- P2: j{4,5} ----
        bv[0] = *(const bf16x8*)(const void*)&Bbuf[bfo[4]];
        bv[1] = *(const bf16x8*)(const void*)&Bbuf[bfo[5]];
        if (kt < 15) { ST_R(2, nb, kt + 1); VWAIT(2); }
        __builtin_amdgcn_s_barrier();
        __builtin_amdgcn_s_setprio(1);
#pragma unroll
        for (int i = 0; i < 4; ++i) {
            acc[i][4] = MFMA16(af[i], bv[0], acc[i][4]);
            acc[i][5] = MFMA16(af[i], bv[1], acc[i][5]);
        }
        __builtin_amdgcn_s_setprio(0);
        __builtin_amdgcn_s_barrier();
    }

    // ---- stash Q,K,V (+bias) into the wave's PRIVATE patch (no block sync) ----
    float bj[6];
#pragma unroll
    for (int j = 0; j < 6; ++j) bj[j] = bias[g * 96 + j * 16 + ln];
    u16t* pw = &pool[w * 6656];
#pragma unroll
    for (int i = 0; i < 4; ++i)
#pragma unroll
        for (int j = 0; j < 6; ++j) {
            int part = j >> 1;                     // 0=Q 1=K 2=V
            int d = (j & 1) * 16 + ln;
#pragma unroll
            for (int rr = 0; rr < 4; ++rr) {
                int tok = i * 16 + qd * 4 + rr;
                bf16 val = (bf16)(acc[i][j][rr] + bj[j]);
                int idx;
                if (part == 2)
                    idx = 4608 + tok * 32 +
                          (((d >> 3) ^ (((tok >> 3) ^ tok) & 3)) << 3) + (d & 7);
                else
                    idx = part * 2048 + tok * 32 +
                          (((d >> 3) ^ ((tok >> 1) & 3)) << 3) + (d & 7);
                *(bf16*)&pw[idx] = val;
            }
        }

    // ---- attention for (win, head g): verbatim validated math ----
    {
        const int hcol = g * 32;
        const int qswz = (qd ^ ((ln >> 1) & 3)) * 8;

        bf16x8 aq[4], bk[4];
#pragma unroll
        for (int i = 0; i < 4; ++i)
            aq[i] = *(const bf16x8*)(const void*)&pw[(i * 16 + ln) * 32 + qswz];
#pragma unroll
        for (int j = 0; j < 4; ++j)
            bk[j] = *(const bf16x8*)(const void*)&pw[2048 + (j * 16 + ln) * 32 + qswz];

        f32x4 zro = {0.f, 0.f, 0.f, 0.f};
        f32x4 s[4][4];
#pragma unroll
        for (int i = 0; i < 4; ++i)
#pragma unroll
            for (int j = 0; j < 4; ++j) s[i][j] = MFMA16(aq[i], bk[j], zro);

        const float INV2S2 = 3.28731097961867f;  // 1/(2*0.39^2)
        {
            int c = lane & 7;
            float S1 = 0.f;
#pragma unroll
            for (int c2 = 0; c2 < 8; ++c2) {
                int dd = c - c2;
                S1 += __expf(-(float)(dd * dd) * INV2S2);
            }
            float invS1 = 1.0f / S1;
            const int ymb = ln >> 3, xm = ln & 7, yq = qd >> 1, xq = (qd & 1) * 4;
            float FY[4][4], FX[4];
#pragma unroll
            for (int i = 0; i < 4; ++i) {
                int yn = 2 * i + yq;
                float gg = __shfl(invS1, yn, 64);
#pragma unroll
                for (int j = 0; j < 4; ++j) {
                    int dy = yn - (2 * j + ymb);
                    FY[i][j] = __expf(-(float)(dy * dy) * INV2S2) * gg;
                }
            }
#pragma unroll
            for (int rr = 0; rr < 4; ++rr) {
                int xn = xq + rr;
                int dx = xn - xm;
                FX[rr] = __expf(-(float)(dx * dx) * INV2S2) * __shfl(invS1, xn, 64);
            }

            const float SCALE = 0.17677669529663687f;  // 1/sqrt(32)
#pragma unroll
            for (int i = 0; i < 4; ++i)
#pragma unroll
                for (int rr = 0; rr < 4; ++rr) {
                    float lj[4];
                    float mx = -1e30f;
#pragma unroll
                    for (int j = 0; j < 4; ++j) {
                        lj[j] = s[i][j][rr] * SCALE * FY[i][j] * FX[rr];
                        mx = fmaxf(mx, lj[j]);
                    }
                    mx = fmaxf(mx, __shfl_xor(mx, 1));
                    mx = fmaxf(mx, __shfl_xor(mx, 2));
                    mx = fmaxf(mx, __shfl_xor(mx, 4));
                    mx = fmaxf(mx, __shfl_xor(mx, 8));
                    float sum = 0.f;
#pragma unroll
                    for (int j = 0; j < 4; ++j) {
                        lj[j] = __expf(lj[j] - mx);
                        sum += lj[j];
                    }
                    sum += __shfl_xor(sum, 1);
                    sum += __shfl_xor(sum, 2);
                    sum += __shfl_xor(sum, 4);
                    sum += __shfl_xor(sum, 8);
                    float inv = 1.0f / sum;
                    int n = i * 16 + qd * 4 + rr;
#pragma unroll
                    for (int j = 0; j < 4; ++j) {
                        bf16 pv = (bf16)(lj[j] * inv);
                        *(bf16*)&pw[n * 72 + j * 16 + ln] = pv;
                    }
                }
        }

        f32x4 o[4][2];
#pragma unroll
        for (int i = 0; i < 4; ++i) {
            o[i][0] = zro;
            o[i][1] = zro;
        }
#pragma unroll
        for (int kc = 0; kc < 64; kc += 32) {
            bf16x8 bv2[2];
#pragma unroll
            for (int j2 = 0; j2 < 2; ++j2) {
                int cc = j2 * 2 + (ln >> 3);
#pragma unroll
                for (int jj = 0; jj < 8; ++jj) {
                    int rv = kc + q8 + jj;
                    bv2[j2][jj] = *(const bf16*)&pw[4608 + rv * 32 +
                                                   ((cc ^ (((rv >> 3) ^ rv) & 3)) << 3) + (ln & 7)];
                }
            }
#pragma unroll
            for (int i = 0; i < 4; ++i) {
                bf16x8 ap = *(const bf16x8*)(const void*)&pw[(i * 16 + ln) * 72 + kc + q8];
#pragma unroll
                for (int j2 = 0; j2 < 2; ++j2) o[i][j2] = MFMA16(ap, bv2[j2], o[i][j2]);
            }
        }
#pragma unroll
        for (int i = 0; i < 4; ++i)
#pragma unroll
            for (int j2 = 0; j2 < 2; ++j2)
#pragma unroll
                for (int rr = 0; rr < 4; ++rr)
                    attnout[((size_t)win * 64 + i * 16 + qd * 4 + rr) * 512 +
                            hcol + j2 * 16 + ln] = (bf16)(o[i][j2][rr]);
    }
}

extern "C" void kernel_launch(void* const* d_in, const int* in_sizes, int n_in,
                              void* d_out, int out_size, void* d_ws, size_t ws_size,
                              hipStream_t stream) {
    const void* x = d_in[0];
    const void* w_qkv = d_in[1];
    const void* b_qkv = d_in[2];
    const void* w_proj = d_in[3];
    const void* b_proj = d_in[4];
    char* ws = (char*)d_ws;
    u32t* flag = (u32t*)(ws + OFF_FLAG);
    bf16* wqkvT = (bf16*)(ws + OFF_WQKVT);
    bf16* wprojT = (bf16*)(ws + OFF_WPROJT);
    float* bq = (float*)(ws + OFF_BQKV);
    float* bp = (float*)(ws + OFF_BPROJ);
    bf16* attnout = (bf16*)(ws + OFF_QKV);
    bf16* xb = (bf16*)(ws + OFF_XB);

    k_detect<<<1, 256, 0, stream>>>((const u16t*)x, flag);
    k_cvt<<<2048, 256, 0, stream>>>((const float*)x, xb, flag);
    k_trans<1536, true><<<dim3(24, 8), 256, 0, stream>>>(w_qkv, wqkvT, flag);
    k_trans<512, false><<<dim3(8, 8), 256, 0, stream>>>(w_proj, wprojT, flag);
    k_bias<<<8, 256, 0, stream>>>(b_qkv, b_proj, flag, ws);
    // fused QKV GEMM + attention: 1024 m-blocks x 8 head-pair blocks, 4 waves ea.
    k_fuse5<<<8192, 256, 0, stream>>>(x, xb, wqkvT, bq, attnout, flag);
    // proj GEMM: [131072,512] @ [512,512] -> d_out
    k_gemm<512><<<1024, 512, 0, stream>>>((const void*)attnout, attnout, wprojT, bp, d_out, flag, 2);
}

// Round 12
// 837.983 us; speedup vs baseline: 1.0313x; 1.0313x over previous
//
#include <hip/hip_runtime.h>
#include <hip/hip_bf16.h>
#include <stdint.h>

typedef __bf16 bf16;
typedef __bf16 bf16x8 __attribute__((ext_vector_type(8)));
typedef float f32x4 __attribute__((ext_vector_type(4)));
typedef unsigned short u16t;
typedef unsigned int u32t;

#define MFMA16(a, b, c) __builtin_amdgcn_mfma_f32_16x16x32_bf16((a), (b), (c), 0, 0, 0)

typedef const void __attribute__((address_space(1))) cg_void;
typedef void __attribute__((address_space(3))) lds_void;
#define GLL16(g, l) __builtin_amdgcn_global_load_lds((cg_void*)(g), (lds_void*)(l), 16, 0, 0)
#define VWAIT(n) asm volatile("s_waitcnt vmcnt(" #n ")" ::: "memory")

// ---------------- ws layout (bytes) ----------------
#define OFF_FLAG   0
#define OFF_BQKV   256
#define OFF_BPROJ  6400
#define OFF_WQKVT  8448
#define OFF_WPROJT 1581312
#define OFF_QKV    2105600      // attn-out (134 MB; qkv never materialized)
#define OFF_XB     404758784    // xb (bf16 x, 134 MB)

// head-triple permutation: reordered-W^T row n <- original qkv col src(n)
// h = n/96, r = n%96, part = r/32 (0=Q,1=K,2=V), d = r%32; src = part*512 + h*32 + d

// Paired-row LDS layout (validated in fuse5, R11 pass):
// LDS-row R (128 B = 8 chunks of 16 B) holds tokens/cols 2R,2R+1.
// logical chunk c: pair-part = c>>2, k-octet = c&3. phys chunk = c ^ (R&7).
// Stage: lane l of inst with base row Rs (Rs%8==0): R = Rs+(l>>3),
// c = (l&7)^(l>>3), elem = 2R+(c>>2), k-off (c&3)*8.
// Frag read: elem r, k-octet qd -> R = r>>1, c = (r&1)*4+qd, phys = c^(R&7).

// ---------------- dtype detector ----------------
__global__ __launch_bounds__(256) void k_detect(const u16t* x, u32t* flag) {
    __shared__ int cnt;
    if (threadIdx.x == 0) cnt = 0;
    __syncthreads();
    u16t h = x[threadIdx.x * 2];
    int e = (h >> 7) & 0xFF;
    int ok = (h == 0) || (e >= 100 && e <= 134);
    atomicAdd(&cnt, ok);
    __syncthreads();
    if (threadIdx.x == 0) flag[0] = (cnt >= 200) ? 1u : 0u;
}

// ---------------- x f32 -> bf16 pre-pass (skipped when input already bf16) ----
__global__ __launch_bounds__(256) void k_cvt(const float* x, bf16* xb, const u32t* flagp) {
    if (flagp[0]) return;
    const size_t TOT = (size_t)131072 * 512;
    size_t i = (size_t)(blockIdx.x * 256 + threadIdx.x) * 8;
    const size_t stride = (size_t)gridDim.x * 256 * 8;
    for (; i < TOT; i += stride) {
        float4 v0 = *(const float4*)(x + i);
        float4 v1 = *(const float4*)(x + i + 4);
        bf16x8 h;
        h[0] = (bf16)v0.x; h[1] = (bf16)v0.y; h[2] = (bf16)v0.z; h[3] = (bf16)v0.w;
        h[4] = (bf16)v1.x; h[5] = (bf16)v1.y; h[6] = (bf16)v1.z; h[7] = (bf16)v1.w;
        *(bf16x8*)(xb + i) = h;
    }
}

// ---------------- weight transpose: W[512][N] -> Wt[N][512] bf16 ----------------
template <int N, bool PERM>
__global__ __launch_bounds__(256) void k_trans(const void* W, bf16* Wt, const u32t* flagp) {
    __shared__ float T[64][65];
    const int isbf = (int)flagp[0];
    const int n0 = blockIdx.x * 64, k0 = blockIdx.y * 64;
    const int t = threadIdx.x;
    const int lc = t & 63, lr = t >> 6;
#pragma unroll
    for (int rr = 0; rr < 16; ++rr) {
        int row = rr * 4 + lr;
        int col = n0 + lc;
        int srcc = col;
        if (PERM) {
            int h = col / 96, r = col % 96;
            srcc = (r >> 5) * 512 + h * 32 + (r & 31);
        }
        size_t g = (size_t)(k0 + row) * N + srcc;
        float v = isbf ? (float)((const bf16*)W)[g] : ((const float*)W)[g];
        T[row][lc] = v;
    }
    __syncthreads();
#pragma unroll
    for (int rr = 0; rr < 16; ++rr) {
        int row = rr * 4 + lr;
        Wt[(size_t)(n0 + row) * 512 + k0 + lc] = (bf16)T[lc][row];
    }
}

// ---------------- bias prep -> f32 (bq permuted to head-triple order) ----------
__global__ __launch_bounds__(256) void k_bias(const void* b_qkv, const void* b_proj,
                                              const u32t* flagp, char* ws) {
    float* bq = (float*)(ws + OFF_BQKV);
    float* bp = (float*)(ws + OFF_BPROJ);
    const int isbf = (int)flagp[0];
    int gid = blockIdx.x * 256 + threadIdx.x;
    if (gid < 1536) {
        int h = gid / 96, r = gid % 96;
        int src = (r >> 5) * 512 + h * 32 + (r & 31);
        bq[gid] = isbf ? (float)((const bf16*)b_qkv)[src] : ((const float*)b_qkv)[src];
    } else if (gid < 2048) {
        int o = gid - 1536;
        bp[o] = isbf ? (float)((const bf16*)b_proj)[o] : ((const float*)b_proj)[o];
    }
}

// ---------------- proj GEMM v2: BM=128 x BN=256, BK=32, 48 KB, 16 waves/CU ----
// 512 thr = 8 waves (wm=w>>2 in {0,1}, wn=w&3); wave tile 64x64, acc[4][4]=64
// VGPR -> total ~110 <= 128 (launch_bounds(512,4) enforces 4 waves/EU = 16/CU).
// K=512 -> 16 tiles BK=32, 2 phases (j-pairs {0,1},{2,3}), 8 MFMA each.
// Stage insts/wave/tile: A=1 (Rs=w*8, rows [0,64)), B0=1 ((w&3)*32+(w>>2)*8 ->
// per-wn rows [wn*32,+16) = j01 cols), B1=B0+16 (j23 cols). All bases %8==0.
// Operand-aware ledger (B = wprojT L2-resident: 1-2 phase slack OK; A = attnout
// HBM: A(t+2) issued at P1(t) -> 3-phase slack):
//   P0(t): issue B0(t+1);        VWAIT(2) -> B1(t) ready for P1(t)
//   P1(t): issue B1(t+1),A(t+2); VWAIT(2) -> A(t+1),B0(t+1) ready for P0(t+1)
// Tail: t=14 P0 VWAIT(2), P1 (B1 only) VWAIT(1); t=15 P0 VWAIT(0), P1 none.
// Prologue: A(0),B0(0),B1(0),A(1); VWAIT(2). Never drains mid-loop.
// Write-hazards: A(t+2)->As[t&1] issued after P0(t)'s post-MFMA barrier (reads
// done); B*(t+1)->Bs[nb] issued >=2 barriers after tile t-1's reads.
// Per-acc K-order: 16 ascending 32-steps (same as all passing rounds).
template <int NTOT>
__global__ __launch_bounds__(512, 4) void k_gemm(const void* Ax, const bf16* Axb, const bf16* Bt,
                                                 const float* bias, void* Cp,
                                                 const u32t* flagp, int omode) {
    __shared__ __align__(16) u16t As[2 * 4096];
    __shared__ __align__(16) u16t Bs[2 * 8192];
    constexpr int NBN = NTOT / 256;
    const int isbf = (int)flagp[0];
    const int out_bf16 = (omode == 1) || isbf;
    const bf16* Ab = isbf ? (const bf16*)Ax : Axb;

    const int t = threadIdx.x;
    const int w = t >> 6, lane = t & 63;
    const int ln = lane & 15, qd = lane >> 4;
    const int wm = w >> 2, wn = w & 3;

    const int flat = blockIdx.x;
    const int xcd = flat & 7, slot = flat >> 3;
    const int n_idx = slot % NBN, mgrp = slot / NBN;
    const int m0 = (mgrp * 8 + xcd) * 128;
    const int n0 = n_idx * 256;

    // staging source (inverse swizzle, paired-row) -- fuse5-validated formulas
    const int l8 = lane >> 3, p8 = lane & 7;
    const int cl = p8 ^ l8;
    const int tok_l = 2 * l8 + (cl >> 2);
    const int koff = (cl & 3) * 8;

    const int RsA = w * 8;
    const u32t asrc = (u32t)(m0 + 2 * RsA + tok_l) * 512 + koff;
    const int adst = RsA * 64;
    const int RsB0 = (w & 3) * 32 + (w >> 2) * 8;
    const u32t bsrc0 = (u32t)(n0 + 2 * RsB0 + tok_l) * 512 + koff;
    const int bdst0 = RsB0 * 64;
    const u32t bsrc1 = bsrc0 + 32 * 512;   // +16 LDS-rows = +32 cols
    const int bdst1 = bdst0 + 16 * 64;

    // fragment bases (paired-row): elem = group*64 + i*16 + (qd*... ) handled
    const int fph = (((ln & 1) * 4 + qd) ^ ((ln >> 1) & 7)) * 8;
    int abase[4], bbase[4];
#pragma unroll
    for (int i = 0; i < 4; ++i) abase[i] = (wm * 32 + i * 8 + (ln >> 1)) * 64 + fph;
#pragma unroll
    for (int j = 0; j < 4; ++j) bbase[j] = (wn * 32 + j * 8 + (ln >> 1)) * 64 + fph;

    f32x4 acc[4][4];
    f32x4 zero = {0.f, 0.f, 0.f, 0.f};
#pragma unroll
    for (int i = 0; i < 4; ++i)
#pragma unroll
        for (int j = 0; j < 4; ++j) acc[i][j] = zero;

    auto stA = [&](int buf, int kt) { GLL16(Ab + asrc + kt * 32, &As[buf * 4096 + adst]); };
    auto stB0 = [&](int buf, int kt) { GLL16(Bt + bsrc0 + kt * 32, &Bs[buf * 8192 + bdst0]); };
    auto stB1 = [&](int buf, int kt) { GLL16(Bt + bsrc1 + kt * 32, &Bs[buf * 8192 + bdst1]); };

    // prologue: A(0),B0(0),B1(0),A(1); need A(0),B0(0) -> VWAIT(2)
    stA(0, 0);
    stB0(0, 0);
    stB1(0, 0);
    stA(1, 1);
    VWAIT(2);
    __builtin_amdgcn_s_barrier();

    for (int kt = 0; kt < 16; ++kt) {
        const int buf = kt & 1, nb = buf ^ 1;
        bf16x8 af[4], bv[2];

        // ---- P0: A frags + j{0,1} ----
#pragma unroll
        for (int i = 0; i < 4; ++i)
            af[i] = *(const bf16x8*)(const void*)&As[buf * 4096 + abase[i]];
        bv[0] = *(const bf16x8*)(const void*)&Bs[buf * 8192 + bbase[0]];
        bv[1] = *(const bf16x8*)(const void*)&Bs[buf * 8192 + bbase[1]];
        if (kt < 15) { stB0(nb, kt + 1); VWAIT(2); }
        else VWAIT(0);
        __builtin_amdgcn_s_barrier();
        __builtin_amdgcn_s_setprio(1);
#pragma unroll
        for (int i = 0; i < 4; ++i) {
            acc[i][0] = MFMA16(af[i], bv[0], acc[i][0]);
            acc[i][1] = MFMA16(af[i], bv[1], acc[i][1]);
        }
        __builtin_amdgcn_s_setprio(0);
        __builtin_amdgcn_s_barrier();

        // ---- P1: j{2,3} ----
        bv[0] = *(const bf16x8*)(const void*)&Bs[buf * 8192 + bbase[2]];
        bv[1] = *(const bf16x8*)(const void*)&Bs[buf * 8192 + bbase[3]];
        if (kt < 15) {
            stB1(nb, kt + 1);
            if (kt < 14) stA(buf, kt + 2);   // A(t+2) -> As[buf], freed at P0(t)
            if (kt < 14) VWAIT(2);
            else VWAIT(1);
        }
        __builtin_amdgcn_s_barrier();
        __builtin_amdgcn_s_setprio(1);
#pragma unroll
        for (int i = 0; i < 4; ++i) {
            acc[i][2] = MFMA16(af[i], bv[0], acc[i][2]);
            acc[i][3] = MFMA16(af[i], bv[1], acc[i][3]);
        }
        __builtin_amdgcn_s_setprio(0);
        __builtin_amdgcn_s_barrier();
    }

    float bj[4];
#pragma unroll
    for (int j = 0; j < 4; ++j) bj[j] = bias[n0 + wn * 64 + j * 16 + ln];

    if (out_bf16) {
        bf16* C = (bf16*)Cp;
#pragma unroll
        for (int i = 0; i < 4; ++i)
#pragma unroll
            for (int j = 0; j < 4; ++j)
#pragma unroll
                for (int rr = 0; rr < 4; ++rr) {
                    size_t row = (size_t)m0 + wm * 64 + i * 16 + qd * 4 + rr;
                    int col = n0 + wn * 64 + j * 16 + ln;
                    C[row * NTOT + col] = (bf16)(acc[i][j][rr] + bj[j]);
                }
    } else {
        float* C = (float*)Cp;
#pragma unroll
        for (int i = 0; i < 4; ++i)
#pragma unroll
            for (int j = 0; j < 4; ++j)
#pragma unroll
                for (int rr = 0; rr < 4; ++rr) {
                    size_t row = (size_t)m0 + wm * 64 + i * 16 + qd * 4 + rr;
                    int col = n0 + wn * 64 + j * 16 + ln;
                    C[row * NTOT + col] = acc[i][j][rr] + bj[j];
                }
    }
}

// ---------------- FUSE5 (unchanged from R11 pass) -----------------------------
__global__ __launch_bounds__(256, 3) void k_fuse5(const void* Ax, const bf16* Axb,
                                                  const bf16* Bt, const float* bias,
                                                  bf16* attnout, const u32t* flagp) {
    __shared__ __align__(16) u16t pool[26624];   // A 2x4096 @0; B 2x6144 @8192
    const int isbf = (int)flagp[0];
    const bf16* Ab = isbf ? (const bf16*)Ax : Axb;

    const int t = threadIdx.x;
    const int w = t >> 6, lane = t & 63;
    const int ln = lane & 15, qd = lane >> 4, q8 = qd * 8;
    const int wm = w >> 1, wn = w & 1;

    const int flat = blockIdx.x;
    const int xcd = flat & 7, slot = flat >> 3;
    const int n_idx = slot & 7, mgrp = slot >> 3;
    const int blkm = mgrp * 8 + xcd;             // 0..1023 (bijective)
    const int m0 = blkm * 128;
    const int n0 = n_idx * 192;
    const int win = blkm * 2 + wm;
    const int g = n_idx * 2 + wn;

    // staging source (inverse swizzle, paired-row)
    const int l8 = lane >> 3, p8 = lane & 7;
    const int cl = p8 ^ l8;
    const int tok_l = 2 * l8 + (cl >> 2);
    const int koff = (cl & 3) * 8;

    // A: 2 insts/wave; inst q base LDS-row w*16+q*8 (covers rows [0,64))
    u32t asrc[2];
    int adst[2];
#pragma unroll
    for (int q = 0; q < 2; ++q) {
        int Rs = w * 16 + q * 8;
        asrc[q] = (u32t)(m0 + 2 * Rs + tok_l) * 512 + koff;
        adst[q] = Rs * 64;
    }
    // B: 1 inst/wave/region; region r covers LDS-rows [r*16,+16)u[48+r*16,+16)
    u32t bsrc[3];
    int bdst[3];
#pragma unroll
    for (int r = 0; r < 3; ++r) {
        int Rs = (w & 1) * 48 + r * 16 + (w >> 1) * 8;
        bsrc[r] = (u32t)(n0 + 2 * Rs + tok_l) * 512 + koff;
        bdst[r] = Rs * 64;
    }

    // fragment bases
    const int fph = (((ln & 1) * 4 + qd) ^ ((ln >> 1) & 7)) * 8;
    int afo[4], bfo[6];
#pragma unroll
    for (int i = 0; i < 4; ++i) afo[i] = (wm * 32 + i * 8 + (ln >> 1)) * 64 + fph;
#pragma unroll
    for (int j = 0; j < 6; ++j) bfo[j] = (wn * 48 + j * 8 + (ln >> 1)) * 64 + fph;

    f32x4 acc[4][6];
    f32x4 zero = {0.f, 0.f, 0.f, 0.f};
#pragma unroll
    for (int i = 0; i < 4; ++i)
#pragma unroll
        for (int j = 0; j < 6; ++j) acc[i][j] = zero;

    auto ST_A = [&](int buf, int kt) {
#pragma unroll
        for (int q = 0; q < 2; ++q)
            GLL16(Ab + asrc[q] + kt * 32, &pool[buf * 4096 + adst[q]]);
    };
    auto ST_R = [&](int r, int buf, int kt) {
        GLL16(Bt + bsrc[r] + kt * 32, &pool[8192 + buf * 6144 + bdst[r]]);
    };

    // prologue: tile 0 -> buf 0 (order A,A,R0,R1,R2); A+R0 needed -> VWAIT(2)
    ST_A(0, 0);
    ST_R(0, 0, 0);
    ST_R(1, 0, 0);
    ST_R(2, 0, 0);
    VWAIT(2);
    __builtin_amdgcn_s_barrier();

    for (int kt = 0; kt < 16; ++kt) {
        const int buf = kt & 1, nb = buf ^ 1;
        const u16t* Abuf = &pool[buf * 4096];
        const u16t* Bbuf = &pool[8192 + buf * 6144];
        bf16x8 af[4], bv[2];

        // ---- P0: A-frags + j{0,1} ----
#pragma unroll
        for (int i = 0; i < 4; ++i)
            af[i] = *(const bf16x8*)(const void*)&Abuf[afo[i]];
        bv[0] = *(const bf16x8*)(const void*)&Bbuf[bfo[0]];
        bv[1] = *(const bf16x8*)(const void*)&Bbuf[bfo[1]];
        if (kt < 15) { ST_A(nb, kt + 1); ST_R(0, nb, kt + 1); VWAIT(4); }
        else VWAIT(1);
        __builtin_amdgcn_s_barrier();
        __builtin_amdgcn_s_setprio(1);
#pragma unroll
        for (int i = 0; i < 4; ++i) {
            acc[i][0] = MFMA16(af[i], bv[0], acc[i][0]);
            acc[i][1] = MFMA16(af[i], bv[1], acc[i][1]);
        }
        __builtin_amdgcn_s_setprio(0);
        __builtin_amdgcn_s_barrier();

        // ---- P1: j{2,3} ----
        bv[0] = *(const bf16x8*)(const void*)&Bbuf[bfo[2]];
        bv[1] = *(const bf16x8*)(const void*)&Bbuf[bfo[3]];
        if (kt < 15) { ST_R(1, nb, kt + 1); VWAIT(4); }
        else VWAIT(0);
        __builtin_amdgcn_s_barrier();
        __builtin_amdgcn_s_setprio(1);
#pragma unroll
        for (int i = 0; i < 4; ++i) {
            acc[i][2] = MFMA16(af[i], bv[0], acc[i][2]);
            acc[i][3] = MFMA16(af[i], bv[1], acc[i][3]);
        }
        __builtin_amdgcn_s_setprio(0);
        __builtin_amdgcn_s_barrier();

        // ---- P2: j{4,5} ----
        bv[0] = *(const bf16x8*)(const void*)&Bbuf[bfo[4]];
        bv[1] = *(const bf16x8*)(const void*)&Bbuf[bfo[5]];
        if (kt < 15) { ST_R(2, nb, kt + 1); VWAIT(2); }
        __builtin_amdgcn_s_barrier();
        __builtin_amdgcn_s_setprio(1);
#pragma unroll
        for (int i = 0; i < 4; ++i) {
            acc[i][4] = MFMA16(af[i], bv[0], acc[i][4]);
            acc[i][5] = MFMA16(af[i], bv[1], acc[i][5]);
        }
        __builtin_amdgcn_s_setprio(0);
        __builtin_amdgcn_s_barrier();
    }

    // ---- stash Q,K,V (+bias) into the wave's PRIVATE patch (no block sync) ----
    float bj[6];
#pragma unroll
    for (int j = 0; j < 6; ++j) bj[j] = bias[g * 96 + j * 16 + ln];
    u16t* pw = &pool[w * 6656];
#pragma unroll
    for (int i = 0; i < 4; ++i)
#pragma unroll
        for (int j = 0; j < 6; ++j) {
            int part = j >> 1;                     // 0=Q 1=K 2=V
            int d = (j & 1) * 16 + ln;
#pragma unroll
            for (int rr = 0; rr < 4; ++rr) {
                int tok = i * 16 + qd * 4 + rr;
                bf16 val = (bf16)(acc[i][j][rr] + bj[j]);
                int idx;
                if (part == 2)
                    idx = 4608 + tok * 32 +
                          (((d >> 3) ^ (((tok >> 3) ^ tok) & 3)) << 3) + (d & 7);
                else
                    idx = part * 2048 + tok * 32 +
                          (((d >> 3) ^ ((tok >> 1) & 3)) << 3) + (d & 7);
                *(bf16*)&pw[idx] = val;
            }
        }

    // ---- attention for (win, head g): verbatim validated math ----
    {
        const int hcol = g * 32;
        const int qswz = (qd ^ ((ln >> 1) & 3)) * 8;

        bf16x8 aq[4], bk[4];
#pragma unroll
        for (int i = 0; i < 4; ++i)
            aq[i] = *(const bf16x8*)(const void*)&pw[(i * 16 + ln) * 32 + qswz];
#pragma unroll
        for (int j = 0; j < 4; ++j)
            bk[j] = *(const bf16x8*)(const void*)&pw[2048 + (j * 16 + ln) * 32 + qswz];

        f32x4 zro = {0.f, 0.f, 0.f, 0.f};
        f32x4 s[4][4];
#pragma unroll
        for (int i = 0; i < 4; ++i)
#pragma unroll
            for (int j = 0; j < 4; ++j) s[i][j] = MFMA16(aq[i], bk[j], zro);

        const float INV2S2 = 3.28731097961867f;  // 1/(2*0.39^2)
        {
            int c = lane & 7;
            float S1 = 0.f;
#pragma unroll
            for (int c2 = 0; c2 < 8; ++c2) {
                int dd = c - c2;
                S1 += __expf(-(float)(dd * dd) * INV2S2);
            }
            float invS1 = 1.0f / S1;
            const int ymb = ln >> 3, xm = ln & 7, yq = qd >> 1, xq = (qd & 1) * 4;
            float FY[4][4], FX[4];
#pragma unroll
            for (int i = 0; i < 4; ++i) {
                int yn = 2 * i + yq;
                float gg = __shfl(invS1, yn, 64);
#pragma unroll
                for (int j = 0; j < 4; ++j) {
                    int dy = yn - (2 * j + ymb);
                    FY[i][j] = __expf(-(float)(dy * dy) * INV2S2) * gg;
                }
            }
#pragma unroll
            for (int rr = 0; rr < 4; ++rr) {
                int xn = xq + rr;
                int dx = xn - xm;
                FX[rr] = __expf(-(float)(dx * dx) * INV2S2) * __shfl(invS1, xn, 64);
            }

            const float SCALE = 0.17677669529663687f;  // 1/sqrt(32)
#pragma unroll
            for (int i = 0; i < 4; ++i)
#pragma unroll
                for (int rr = 0; rr < 4; ++rr) {
                    float lj[4];
                    float mx = -1e30f;
#pragma unroll
                    for (int j = 0; j < 4; ++j) {
                        lj[j] = s[i][j][rr] * SCALE * FY[i][j] * FX[rr];
                        mx = fmaxf(mx, lj[j]);
                    }
                    mx = fmaxf(mx, __shfl_xor(mx, 1));
                    mx = fmaxf(mx, __shfl_xor(mx, 2));
                    mx = fmaxf(mx, __shfl_xor(mx, 4));
                    mx = fmaxf(mx, __shfl_xor(mx, 8));
                    float sum = 0.f;
#pragma unroll
                    for (int j = 0; j < 4; ++j) {
                        lj[j] = __expf(lj[j] - mx);
                        sum += lj[j];
                    }
                    sum += __shfl_xor(sum, 1);
                    sum += __shfl_xor(sum, 2);
                    sum += __shfl_xor(sum, 4);
                    sum += __shfl_xor(sum, 8);
                    float inv = 1.0f / sum;
                    int n = i * 16 + qd * 4 + rr;
#pragma unroll
                    for (int j = 0; j < 4; ++j) {
                        bf16 pv = (bf16)(lj[j] * inv);
                        *(bf16*)&pw[n * 72 + j * 16 + ln] = pv;
                    }
                }
        }

        f32x4 o[4][2];
#pragma unroll
        for (int i = 0; i < 4; ++i) {
            o[i][0] = zro;
            o[i][1] = zro;
        }
#pragma unroll
        for (int kc = 0; kc < 64; kc += 32) {
            bf16x8 bv2[2];
#pragma unroll
            for (int j2 = 0; j2 < 2; ++j2) {
                int cc = j2 * 2 + (ln >> 3);
#pragma unroll
                for (int jj = 0; jj < 8; ++jj) {
                    int rv = kc + q8 + jj;
                    bv2[j2][jj] = *(const bf16*)&pw[4608 + rv * 32 +
                                                   ((cc ^ (((rv >> 3) ^ rv) & 3)) << 3) + (ln & 7)];
                }
            }
#pragma unroll
            for (int i = 0; i < 4; ++i) {
                bf16x8 ap = *(const bf16x8*)(const void*)&pw[(i * 16 + ln) * 72 + kc + q8];
#pragma unroll
                for (int j2 = 0; j2 < 2; ++j2) o[i][j2] = MFMA16(ap, bv2[j2], o[i][j2]);
            }
        }
#pragma unroll
        for (int i = 0; i < 4; ++i)
#pragma unroll
            for (int j2 = 0; j2 < 2; ++j2)
#pragma unroll
                for (int rr = 0; rr < 4; ++rr)
                    attnout[((size_t)win * 64 + i * 16 + qd * 4 + rr) * 512 +
                            hcol + j2 * 16 + ln] = (bf16)(o[i][j2][rr]);
    }
}

extern "C" void kernel_launch(void* const* d_in, const int* in_sizes, int n_in,
                              void* d_out, int out_size, void* d_ws, size_t ws_size,
                              hipStream_t stream) {
    const void* x = d_in[0];
    const void* w_qkv = d_in[1];
    const void* b_qkv = d_in[2];
    const void* w_proj = d_in[3];
    const void* b_proj = d_in[4];
    char* ws = (char*)d_ws;
    u32t* flag = (u32t*)(ws + OFF_FLAG);
    bf16* wqkvT = (bf16*)(ws + OFF_WQKVT);
    bf16* wprojT = (bf16*)(ws + OFF_WPROJT);
    float* bq = (float*)(ws + OFF_BQKV);
    float* bp = (float*)(ws + OFF_BPROJ);
    bf16* attnout = (bf16*)(ws + OFF_QKV);
    bf16* xb = (bf16*)(ws + OFF_XB);

    k_detect<<<1, 256, 0, stream>>>((const u16t*)x, flag);
    k_cvt<<<2048, 256, 0, stream>>>((const float*)x, xb, flag);
    k_trans<1536, true><<<dim3(24, 8), 256, 0, stream>>>(w_qkv, wqkvT, flag);
    k_trans<512, false><<<dim3(8, 8), 256, 0, stream>>>(w_proj, wprojT, flag);
    k_bias<<<8, 256, 0, stream>>>(b_qkv, b_proj, flag, ws);
    // fused QKV GEMM + attention: 1024 m-blocks x 8 head-pair blocks, 4 waves ea.
    k_fuse5<<<8192, 256, 0, stream>>>(x, xb, wqkvT, bq, attnout, flag);
    // proj GEMM v2: 1024 m-blocks x 2 n-blocks = 2048 blocks, 512 thr
    k_gemm<512><<<2048, 512, 0, stream>>>((const void*)attnout, attnout, wprojT, bp, d_out, flag, 2);
}

// Round 13
// 831.981 us; speedup vs baseline: 1.0388x; 1.0072x over previous
//
#include <hip/hip_runtime.h>
#include <hip/hip_bf16.h>
#include <stdint.h>

typedef __bf16 bf16;
typedef __bf16 bf16x8 __attribute__((ext_vector_type(8)));
typedef float f32x4 __attribute__((ext_vector_type(4)));
typedef unsigned short u16t;
typedef unsigned int u32t;

#define MFMA16(a, b, c) __builtin_amdgcn_mfma_f32_16x16x32_bf16((a), (b), (c), 0, 0, 0)

typedef const void __attribute__((address_space(1))) cg_void;
typedef void __attribute__((address_space(3))) lds_void;
#define GLL16(g, l) __builtin_amdgcn_global_load_lds((cg_void*)(g), (lds_void*)(l), 16, 0, 0)
#define VWAIT(n) asm volatile("s_waitcnt vmcnt(" #n ")" ::: "memory")

// ---------------- ws layout (bytes) ----------------
#define OFF_FLAG   0
#define OFF_BQKV   256
#define OFF_BPROJ  6400
#define OFF_WQKVT  8448
#define OFF_WPROJT 1581312
#define OFF_QKV    2105600      // attn-out (134 MB; qkv never materialized)
#define OFF_XB     404758784    // xb (bf16 x, 134 MB)

// head-triple permutation: reordered-W^T row n <- original qkv col src(n)
// h = n/96, r = n%96, part = r/32 (0=Q,1=K,2=V), d = r%32; src = part*512 + h*32 + d

// Paired-row LDS layout (validated fuse5/R11-R12):
// LDS-row R (128 B = 8 chunks of 16 B) holds tokens/cols 2R,2R+1.
// logical chunk c: pair-part = c>>2, k-octet = c&3. phys chunk = c ^ (R&7).
// Stage: lane l of inst with base row Rs (Rs%8==0): R = Rs+(l>>3),
// c = (l&7)^(l>>3), elem = 2R+(c>>2), k-off (c&3)*8.
// Frag read: elem r, k-octet qd -> R = r>>1, c = (r&1)*4+qd, phys = c^(R&7).
//
// R13 change: ONE barrier per phase (pre-MFMA). Safety proof: all LDS reads of
// a phase precede its barrier; MFMA is register-only; stage writes target
// regions whose last reads preceded an earlier barrier (double-buffer +
// disjoint stage regions); every VWAIT precedes the surviving barrier, so the
// validated ledgers carry over unchanged. Data path untouched -> absmax
// bit-identical (tripwire).

// ---------------- dtype detector ----------------
__global__ __launch_bounds__(256) void k_detect(const u16t* x, u32t* flag) {
    __shared__ int cnt;
    if (threadIdx.x == 0) cnt = 0;
    __syncthreads();
    u16t h = x[threadIdx.x * 2];
    int e = (h >> 7) & 0xFF;
    int ok = (h == 0) || (e >= 100 && e <= 134);
    atomicAdd(&cnt, ok);
    __syncthreads();
    if (threadIdx.x == 0) flag[0] = (cnt >= 200) ? 1u : 0u;
}

// ---------------- x f32 -> bf16 pre-pass (skipped when input already bf16) ----
__global__ __launch_bounds__(256) void k_cvt(const float* x, bf16* xb, const u32t* flagp) {
    if (flagp[0]) return;
    const size_t TOT = (size_t)131072 * 512;
    size_t i = (size_t)(blockIdx.x * 256 + threadIdx.x) * 8;
    const size_t stride = (size_t)gridDim.x * 256 * 8;
    for (; i < TOT; i += stride) {
        float4 v0 = *(const float4*)(x + i);
        float4 v1 = *(const float4*)(x + i + 4);
        bf16x8 h;
        h[0] = (bf16)v0.x; h[1] = (bf16)v0.y; h[2] = (bf16)v0.z; h[3] = (bf16)v0.w;
        h[4] = (bf16)v1.x; h[5] = (bf16)v1.y; h[6] = (bf16)v1.z; h[7] = (bf16)v1.w;
        *(bf16x8*)(xb + i) = h;
    }
}

// ---------------- weight transpose: W[512][N] -> Wt[N][512] bf16 ----------------
template <int N, bool PERM>
__global__ __launch_bounds__(256) void k_trans(const void* W, bf16* Wt, const u32t* flagp) {
    __shared__ float T[64][65];
    const int isbf = (int)flagp[0];
    const int n0 = blockIdx.x * 64, k0 = blockIdx.y * 64;
    const int t = threadIdx.x;
    const int lc = t & 63, lr = t >> 6;
#pragma unroll
    for (int rr = 0; rr < 16; ++rr) {
        int row = rr * 4 + lr;
        int col = n0 + lc;
        int srcc = col;
        if (PERM) {
            int h = col / 96, r = col % 96;
            srcc = (r >> 5) * 512 + h * 32 + (r & 31);
        }
        size_t g = (size_t)(k0 + row) * N + srcc;
        float v = isbf ? (float)((const bf16*)W)[g] : ((const float*)W)[g];
        T[row][lc] = v;
    }
    __syncthreads();
#pragma unroll
    for (int rr = 0; rr < 16; ++rr) {
        int row = rr * 4 + lr;
        Wt[(size_t)(n0 + row) * 512 + k0 + lc] = (bf16)T[lc][row];
    }
}

// ---------------- bias prep -> f32 (bq permuted to head-triple order) ----------
__global__ __launch_bounds__(256) void k_bias(const void* b_qkv, const void* b_proj,
                                              const u32t* flagp, char* ws) {
    float* bq = (float*)(ws + OFF_BQKV);
    float* bp = (float*)(ws + OFF_BPROJ);
    const int isbf = (int)flagp[0];
    int gid = blockIdx.x * 256 + threadIdx.x;
    if (gid < 1536) {
        int h = gid / 96, r = gid % 96;
        int src = (r >> 5) * 512 + h * 32 + (r & 31);
        bq[gid] = isbf ? (float)((const bf16*)b_qkv)[src] : ((const float*)b_qkv)[src];
    } else if (gid < 2048) {
        int o = gid - 1536;
        bp[o] = isbf ? (float)((const bf16*)b_proj)[o] : ((const float*)b_proj)[o];
    }
}

// ---------------- proj GEMM v2 (R12 pass) + single-barrier phases -------------
template <int NTOT>
__global__ __launch_bounds__(512, 4) void k_gemm(const void* Ax, const bf16* Axb, const bf16* Bt,
                                                 const float* bias, void* Cp,
                                                 const u32t* flagp, int omode) {
    __shared__ __align__(16) u16t As[2 * 4096];
    __shared__ __align__(16) u16t Bs[2 * 8192];
    constexpr int NBN = NTOT / 256;
    const int isbf = (int)flagp[0];
    const int out_bf16 = (omode == 1) || isbf;
    const bf16* Ab = isbf ? (const bf16*)Ax : Axb;

    const int t = threadIdx.x;
    const int w = t >> 6, lane = t & 63;
    const int ln = lane & 15, qd = lane >> 4;
    const int wm = w >> 2, wn = w & 3;

    const int flat = blockIdx.x;
    const int xcd = flat & 7, slot = flat >> 3;
    const int n_idx = slot % NBN, mgrp = slot / NBN;
    const int m0 = (mgrp * 8 + xcd) * 128;
    const int n0 = n_idx * 256;

    // staging source (inverse swizzle, paired-row)
    const int l8 = lane >> 3, p8 = lane & 7;
    const int cl = p8 ^ l8;
    const int tok_l = 2 * l8 + (cl >> 2);
    const int koff = (cl & 3) * 8;

    const int RsA = w * 8;
    const u32t asrc = (u32t)(m0 + 2 * RsA + tok_l) * 512 + koff;
    const int adst = RsA * 64;
    const int RsB0 = (w & 3) * 32 + (w >> 2) * 8;
    const u32t bsrc0 = (u32t)(n0 + 2 * RsB0 + tok_l) * 512 + koff;
    const int bdst0 = RsB0 * 64;
    const u32t bsrc1 = bsrc0 + 32 * 512;   // +16 LDS-rows = +32 cols
    const int bdst1 = bdst0 + 16 * 64;

    const int fph = (((ln & 1) * 4 + qd) ^ ((ln >> 1) & 7)) * 8;
    int abase[4], bbase[4];
#pragma unroll
    for (int i = 0; i < 4; ++i) abase[i] = (wm * 32 + i * 8 + (ln >> 1)) * 64 + fph;
#pragma unroll
    for (int j = 0; j < 4; ++j) bbase[j] = (wn * 32 + j * 8 + (ln >> 1)) * 64 + fph;

    f32x4 acc[4][4];
    f32x4 zero = {0.f, 0.f, 0.f, 0.f};
#pragma unroll
    for (int i = 0; i < 4; ++i)
#pragma unroll
        for (int j = 0; j < 4; ++j) acc[i][j] = zero;

    auto stA = [&](int buf, int kt) { GLL16(Ab + asrc + kt * 32, &As[buf * 4096 + adst]); };
    auto stB0 = [&](int buf, int kt) { GLL16(Bt + bsrc0 + kt * 32, &Bs[buf * 8192 + bdst0]); };
    auto stB1 = [&](int buf, int kt) { GLL16(Bt + bsrc1 + kt * 32, &Bs[buf * 8192 + bdst1]); };

    // prologue: A(0),B0(0),B1(0),A(1); need A(0),B0(0) -> VWAIT(2)
    stA(0, 0);
    stB0(0, 0);
    stB1(0, 0);
    stA(1, 1);
    VWAIT(2);
    __builtin_amdgcn_s_barrier();

    for (int kt = 0; kt < 16; ++kt) {
        const int buf = kt & 1, nb = buf ^ 1;
        bf16x8 af[4], bv[2];

        // ---- P0: A frags + j{0,1} ----
#pragma unroll
        for (int i = 0; i < 4; ++i)
            af[i] = *(const bf16x8*)(const void*)&As[buf * 4096 + abase[i]];
        bv[0] = *(const bf16x8*)(const void*)&Bs[buf * 8192 + bbase[0]];
        bv[1] = *(const bf16x8*)(const void*)&Bs[buf * 8192 + bbase[1]];
        if (kt < 15) { stB0(nb, kt + 1); VWAIT(2); }
        else VWAIT(0);
        __builtin_amdgcn_s_barrier();
        __builtin_amdgcn_s_setprio(1);
#pragma unroll
        for (int i = 0; i < 4; ++i) {
            acc[i][0] = MFMA16(af[i], bv[0], acc[i][0]);
            acc[i][1] = MFMA16(af[i], bv[1], acc[i][1]);
        }
        __builtin_amdgcn_s_setprio(0);

        // ---- P1: j{2,3} ----
        bv[0] = *(const bf16x8*)(const void*)&Bs[buf * 8192 + bbase[2]];
        bv[1] = *(const bf16x8*)(const void*)&Bs[buf * 8192 + bbase[3]];
        if (kt < 15) {
            stB1(nb, kt + 1);
            if (kt < 14) stA(buf, kt + 2);   // A(t+2) -> As[buf], reads done at P0(t)
            if (kt < 14) VWAIT(2);
            else VWAIT(1);
        }
        __builtin_amdgcn_s_barrier();
        __builtin_amdgcn_s_setprio(1);
#pragma unroll
        for (int i = 0; i < 4; ++i) {
            acc[i][2] = MFMA16(af[i], bv[0], acc[i][2]);
            acc[i][3] = MFMA16(af[i], bv[1], acc[i][3]);
        }
        __builtin_amdgcn_s_setprio(0);
    }

    float bj[4];
#pragma unroll
    for (int j = 0; j < 4; ++j) bj[j] = bias[n0 + wn * 64 + j * 16 + ln];

    if (out_bf16) {
        bf16* C = (bf16*)Cp;
#pragma unroll
        for (int i = 0; i < 4; ++i)
#pragma unroll
            for (int j = 0; j < 4; ++j)
#pragma unroll
                for (int rr = 0; rr < 4; ++rr) {
                    size_t row = (size_t)m0 + wm * 64 + i * 16 + qd * 4 + rr;
                    int col = n0 + wn * 64 + j * 16 + ln;
                    C[row * NTOT + col] = (bf16)(acc[i][j][rr] + bj[j]);
                }
    } else {
        float* C = (float*)Cp;
#pragma unroll
        for (int i = 0; i < 4; ++i)
#pragma unroll
            for (int j = 0; j < 4; ++j)
#pragma unroll
                for (int rr = 0; rr < 4; ++rr) {
                    size_t row = (size_t)m0 + wm * 64 + i * 16 + qd * 4 + rr;
                    int col = n0 + wn * 64 + j * 16 + ln;
                    C[row * NTOT + col] = acc[i][j][rr] + bj[j];
                }
    }
}

// ---------------- FUSE5 (R11/R12 pass) + single-barrier phases ----------------
__global__ __launch_bounds__(256, 3) void k_fuse5(const void* Ax, const bf16* Axb,
                                                  const bf16* Bt, const float* bias,
                                                  bf16* attnout, const u32t* flagp) {
    __shared__ __align__(16) u16t pool[26624];   // A 2x4096 @0; B 2x6144 @8192
    const int isbf = (int)flagp[0];
    const bf16* Ab = isbf ? (const bf16*)Ax : Axb;

    const int t = threadIdx.x;
    const int w = t >> 6, lane = t & 63;
    const int ln = lane & 15, qd = lane >> 4, q8 = qd * 8;
    const int wm = w >> 1, wn = w & 1;

    const int flat = blockIdx.x;
    const int xcd = flat & 7, slot = flat >> 3;
    const int n_idx = slot & 7, mgrp = slot >> 3;
    const int blkm = mgrp * 8 + xcd;             // 0..1023 (bijective)
    const int m0 = blkm * 128;
    const int n0 = n_idx * 192;
    const int win = blkm * 2 + wm;
    const int g = n_idx * 2 + wn;

    // staging source (inverse swizzle, paired-row)
    const int l8 = lane >> 3, p8 = lane & 7;
    const int cl = p8 ^ l8;
    const int tok_l = 2 * l8 + (cl >> 2);
    const int koff = (cl & 3) * 8;

    u32t asrc[2];
    int adst[2];
#pragma unroll
    for (int q = 0; q < 2; ++q) {
        int Rs = w * 16 + q * 8;
        asrc[q] = (u32t)(m0 + 2 * Rs + tok_l) * 512 + koff;
        adst[q] = Rs * 64;
    }
    u32t bsrc[3];
    int bdst[3];
#pragma unroll
    for (int r = 0; r < 3; ++r) {
        int Rs = (w & 1) * 48 + r * 16 + (w >> 1) * 8;
        bsrc[r] = (u32t)(n0 + 2 * Rs + tok_l) * 512 + koff;
        bdst[r] = Rs * 64;
    }

    const int fph = (((ln & 1) * 4 + qd) ^ ((ln >> 1) & 7)) * 8;
    int afo[4], bfo[6];
#pragma unroll
    for (int i = 0; i < 4; ++i) afo[i] = (wm * 32 + i * 8 + (ln >> 1)) * 64 + fph;
#pragma unroll
    for (int j = 0; j < 6; ++j) bfo[j] = (wn * 48 + j * 8 + (ln >> 1)) * 64 + fph;

    f32x4 acc[4][6];
    f32x4 zero = {0.f, 0.f, 0.f, 0.f};
#pragma unroll
    for (int i = 0; i < 4; ++i)
#pragma unroll
        for (int j = 0; j < 6; ++j) acc[i][j] = zero;

    auto ST_A = [&](int buf, int kt) {
#pragma unroll
        for (int q = 0; q < 2; ++q)
            GLL16(Ab + asrc[q] + kt * 32, &pool[buf * 4096 + adst[q]]);
    };
    auto ST_R = [&](int r, int buf, int kt) {
        GLL16(Bt + bsrc[r] + kt * 32, &pool[8192 + buf * 6144 + bdst[r]]);
    };

    // prologue: tile 0 -> buf 0 (order A,A,R0,R1,R2); A+R0 needed -> VWAIT(2)
    ST_A(0, 0);
    ST_R(0, 0, 0);
    ST_R(1, 0, 0);
    ST_R(2, 0, 0);
    VWAIT(2);
    __builtin_amdgcn_s_barrier();

    for (int kt = 0; kt < 16; ++kt) {
        const int buf = kt & 1, nb = buf ^ 1;
        const u16t* Abuf = &pool[buf * 4096];
        const u16t* Bbuf = &pool[8192 + buf * 6144];
        bf16x8 af[4], bv[2];

        // ---- P0: A-frags + j{0,1} ----
#pragma unroll
        for (int i = 0; i < 4; ++i)
            af[i] = *(const bf16x8*)(const void*)&Abuf[afo[i]];
        bv[0] = *(const bf16x8*)(const void*)&Bbuf[bfo[0]];
        bv[1] = *(const bf16x8*)(const void*)&Bbuf[bfo[1]];
        if (kt < 15) { ST_A(nb, kt + 1); ST_R(0, nb, kt + 1); VWAIT(4); }
        else VWAIT(1);
        __builtin_amdgcn_s_barrier();
        __builtin_amdgcn_s_setprio(1);
#pragma unroll
        for (int i = 0; i < 4; ++i) {
            acc[i][0] = MFMA16(af[i], bv[0], acc[i][0]);
            acc[i][1] = MFMA16(af[i], bv[1], acc[i][1]);
        }
        __builtin_amdgcn_s_setprio(0);

        // ---- P1: j{2,3} ----
        bv[0] = *(const bf16x8*)(const void*)&Bbuf[bfo[2]];
        bv[1] = *(const bf16x8*)(const void*)&Bbuf[bfo[3]];
        if (kt < 15) { ST_R(1, nb, kt + 1); VWAIT(4); }
        else VWAIT(0);
        __builtin_amdgcn_s_barrier();
        __builtin_amdgcn_s_setprio(1);
#pragma unroll
        for (int i = 0; i < 4; ++i) {
            acc[i][2] = MFMA16(af[i], bv[0], acc[i][2]);
            acc[i][3] = MFMA16(af[i], bv[1], acc[i][3]);
        }
        __builtin_amdgcn_s_setprio(0);

        // ---- P2: j{4,5} ----
        bv[0] = *(const bf16x8*)(const void*)&Bbuf[bfo[4]];
        bv[1] = *(const bf16x8*)(const void*)&Bbuf[bfo[5]];
        if (kt < 15) { ST_R(2, nb, kt + 1); VWAIT(2); }
        __builtin_amdgcn_s_barrier();
        __builtin_amdgcn_s_setprio(1);
#pragma unroll
        for (int i = 0; i < 4; ++i) {
            acc[i][4] = MFMA16(af[i], bv[0], acc[i][4]);
            acc[i][5] = MFMA16(af[i], bv[1], acc[i][5]);
        }
        __builtin_amdgcn_s_setprio(0);
    }

    // ---- stash Q,K,V (+bias) into the wave's PRIVATE patch ----
    // Safe without extra barrier: all waves' final LDS reads preceded the
    // P2(15) barrier every wave has passed before reaching here.
    float bj[6];
#pragma unroll
    for (int j = 0; j < 6; ++j) bj[j] = bias[g * 96 + j * 16 + ln];
    u16t* pw = &pool[w * 6656];
#pragma unroll
    for (int i = 0; i < 4; ++i)
#pragma unroll
        for (int j = 0; j < 6; ++j) {
            int part = j >> 1;                     // 0=Q 1=K 2=V
            int d = (j & 1) * 16 + ln;
#pragma unroll
            for (int rr = 0; rr < 4; ++rr) {
                int tok = i * 16 + qd * 4 + rr;
                bf16 val = (bf16)(acc[i][j][rr] + bj[j]);
                int idx;
                if (part == 2)
                    idx = 4608 + tok * 32 +
                          (((d >> 3) ^ (((tok >> 3) ^ tok) & 3)) << 3) + (d & 7);
                else
                    idx = part * 2048 + tok * 32 +
                          (((d >> 3) ^ ((tok >> 1) & 3)) << 3) + (d & 7);
                *(bf16*)&pw[idx] = val;
            }
        }

    // ---- attention for (win, head g): verbatim validated math ----
    {
        const int hcol = g * 32;
        const int qswz = (qd ^ ((ln >> 1) & 3)) * 8;

        bf16x8 aq[4], bk[4];
#pragma unroll
        for (int i = 0; i < 4; ++i)
            aq[i] = *(const bf16x8*)(const void*)&pw[(i * 16 + ln) * 32 + qswz];
#pragma unroll
        for (int j = 0; j < 4; ++j)
            bk[j] = *(const bf16x8*)(const void*)&pw[2048 + (j * 16 + ln) * 32 + qswz];

        f32x4 zro = {0.f, 0.f, 0.f, 0.f};
        f32x4 s[4][4];
#pragma unroll
        for (int i = 0; i < 4; ++i)
#pragma unroll
            for (int j = 0; j < 4; ++j) s[i][j] = MFMA16(aq[i], bk[j], zro);

        const float INV2S2 = 3.28731097961867f;  // 1/(2*0.39^2)
        {
            int c = lane & 7;
            float S1 = 0.f;
#pragma unroll
            for (int c2 = 0; c2 < 8; ++c2) {
                int dd = c - c2;
                S1 += __expf(-(float)(dd * dd) * INV2S2);
            }
            float invS1 = 1.0f / S1;
            const int ymb = ln >> 3, xm = lane & 7, yq = qd >> 1, xq = (qd & 1) * 4;
            float FY[4][4], FX[4];
#pragma unroll
            for (int i = 0; i < 4; ++i) {
                int yn = 2 * i + yq;
                float gg = __shfl(invS1, yn, 64);
#pragma unroll
                for (int j = 0; j < 4; ++j) {
                    int dy = yn - (2 * j + ymb);
                    FY[i][j] = __expf(-(float)(dy * dy) * INV2S2) * gg;
                }
            }
#pragma unroll
            for (int rr = 0; rr < 4; ++rr) {
                int xn = xq + rr;
                int dx = xn - (ln & 7);
                FX[rr] = __expf(-(float)(dx * dx) * INV2S2) * __shfl(invS1, xn, 64);
            }

            const float SCALE = 0.17677669529663687f;  // 1/sqrt(32)
#pragma unroll
            for (int i = 0; i < 4; ++i)
#pragma unroll
                for (int rr = 0; rr < 4; ++rr) {
                    float lj[4];
                    float mx = -1e30f;
#pragma unroll
                    for (int j = 0; j < 4; ++j) {
                        lj[j] = s[i][j][rr] * SCALE * FY[i][j] * FX[rr];
                        mx = fmaxf(mx, lj[j]);
                    }
                    mx = fmaxf(mx, __shfl_xor(mx, 1));
                    mx = fmaxf(mx, __shfl_xor(mx, 2));
                    mx = fmaxf(mx, __shfl_xor(mx, 4));
                    mx = fmaxf(mx, __shfl_xor(mx, 8));
                    float sum = 0.f;
#pragma unroll
                    for (int j = 0; j < 4; ++j) {
                        lj[j] = __expf(lj[j] - mx);
                        sum += lj[j];
                    }
                    sum += __shfl_xor(sum, 1);
                    sum += __shfl_xor(sum, 2);
                    sum += __shfl_xor(sum, 4);
                    sum += __shfl_xor(sum, 8);
                    float inv = 1.0f / sum;
                    int n = i * 16 + qd * 4 + rr;
#pragma unroll
                    for (int j = 0; j < 4; ++j) {
                        bf16 pv = (bf16)(lj[j] * inv);
                        *(bf16*)&pw[n * 72 + j * 16 + ln] = pv;
                    }
                }
        }

        f32x4 o[4][2];
#pragma unroll
        for (int i = 0; i < 4; ++i) {
            o[i][0] = zro;
            o[i][1] = zro;
        }
#pragma unroll
        for (int kc = 0; kc < 64; kc += 32) {
            bf16x8 bv2[2];
#pragma unroll
            for (int j2 = 0; j2 < 2; ++j2) {
                int cc = j2 * 2 + (ln >> 3);
#pragma unroll
                for (int jj = 0; jj < 8; ++jj) {
                    int rv = kc + q8 + jj;
                    bv2[j2][jj] = *(const bf16*)&pw[4608 + rv * 32 +
                                                   ((cc ^ (((rv >> 3) ^ rv) & 3)) << 3) + (ln & 7)];
                }
            }
#pragma unroll
            for (int i = 0; i < 4; ++i) {
                bf16x8 ap = *(const bf16x8*)(const void*)&pw[(i * 16 + ln) * 72 + kc + q8];
#pragma unroll
                for (int j2 = 0; j2 < 2; ++j2) o[i][j2] = MFMA16(ap, bv2[j2], o[i][j2]);
            }
        }
#pragma unroll
        for (int i = 0; i < 4; ++i)
#pragma unroll
            for (int j2 = 0; j2 < 2; ++j2)
#pragma unroll
                for (int rr = 0; rr < 4; ++rr)
                    attnout[((size_t)win * 64 + i * 16 + qd * 4 + rr) * 512 +
                            hcol + j2 * 16 + ln] = (bf16)(o[i][j2][rr]);
    }
}

extern "C" void kernel_launch(void* const* d_in, const int* in_sizes, int n_in,
                              void* d_out, int out_size, void* d_ws, size_t ws_size,
                              hipStream_t stream) {
    const void* x = d_in[0];
    const void* w_qkv = d_in[1];
    const void* b_qkv = d_in[2];
    const void* w_proj = d_in[3];
    const void* b_proj = d_in[4];
    char* ws = (char*)d_ws;
    u32t* flag = (u32t*)(ws + OFF_FLAG);
    bf16* wqkvT = (bf16*)(ws + OFF_WQKVT);
    bf16* wprojT = (bf16*)(ws + OFF_WPROJT);
    float* bq = (float*)(ws + OFF_BQKV);
    float* bp = (float*)(ws + OFF_BPROJ);
    bf16* attnout = (bf16*)(ws + OFF_QKV);
    bf16* xb = (bf16*)(ws + OFF_XB);

    k_detect<<<1, 256, 0, stream>>>((const u16t*)x, flag);
    k_cvt<<<2048, 256, 0, stream>>>((const float*)x, xb, flag);
    k_trans<1536, true><<<dim3(24, 8), 256, 0, stream>>>(w_qkv, wqkvT, flag);
    k_trans<512, false><<<dim3(8, 8), 256, 0, stream>>>(w_proj, wprojT, flag);
    k_bias<<<8, 256, 0, stream>>>(b_qkv, b_proj, flag, ws);
    // fused QKV GEMM + attention: 1024 m-blocks x 8 head-pair blocks, 4 waves ea.
    k_fuse5<<<8192, 256, 0, stream>>>(x, xb, wqkvT, bq, attnout, flag);
    // proj GEMM v2: 1024 m-blocks x 2 n-blocks = 2048 blocks, 512 thr
    k_gemm<512><<<2048, 512, 0, stream>>>((const void*)attnout, attnout, wprojT, bp, d_out, flag, 2);
}